// Round 1
// baseline (6644.051 us; speedup 1.0000x reference)
//
#include <hip/hip_runtime.h>
#include <math.h>

#define N_NODES 100000
#define N_EDGES 1600000
#define N_REL   3
#define F_DIM   128
#define H_DIM   64
#define O_DIM   32
#define B_NODES 50000
#define BN_EPS  1e-5f

// ---------------------------------------------------------------- degree
__global__ __launch_bounds__(256) void k_deg(const int* __restrict__ dst,
                                             float* __restrict__ deg) {
    int e = blockIdx.x * 256 + threadIdx.x;
    if (e < N_EDGES) atomicAdd(&deg[dst[e]], 1.0f);
}

__global__ __launch_bounds__(256) void k_dinv(float* __restrict__ deg) {
    int n = blockIdx.x * 256 + threadIdx.x;
    if (n < N_NODES) {
        float d = deg[n];
        deg[n] = rsqrtf(fmaxf(d, 1.0f));   // becomes dinv in place
    }
}

// ---------------------------------------------------------------- GEMM
// Y[n][c] = bias[c] + sum_k X[n][k] * W[k][c]
// If BN: X element is first transformed relu(x*se[k] + be[k]).
template<int K, int C, bool BN>
__global__ __launch_bounds__(256) void k_gemm(const float* __restrict__ X,
                                              const float* __restrict__ W,
                                              const float* __restrict__ bias,
                                              const float* __restrict__ se,
                                              const float* __restrict__ be,
                                              float* __restrict__ Y,
                                              int nodesPerBlock) {
    constexpr int CG = C / 4;        // float4 groups per row
    constexpr int NPASS = 256 / CG;  // nodes computed per pass
    constexpr int XP = K + 1;        // padded pitch (break 4-way bank conflict)
    __shared__ __align__(16) float Ws[K * C];
    __shared__ float Xs[NPASS * XP];
    const int tid = threadIdx.x;
    for (int i = tid; i < K * C; i += 256) Ws[i] = W[i];
    const int cg = tid % CG;
    const int ln = tid / CG;
    const int c0 = cg * 4;
    const float4 bv = *(const float4*)&bias[c0];
    const int blockStart = blockIdx.x * nodesPerBlock;
    const int passes = nodesPerBlock / NPASS;
    for (int p = 0; p < passes; ++p) {
        const int node0 = blockStart + p * NPASS;
        __syncthreads();  // Xs free (also covers Ws on first pass)
        for (int i = tid; i < NPASS * K; i += 256) {
            int lnn = i / K, k = i % K;
            int n = node0 + lnn;
            float v = 0.0f;
            if (n < N_NODES) {
                v = X[(size_t)n * K + k];
                if (BN) v = fmaxf(v * se[k] + be[k], 0.0f);
            }
            Xs[lnn * XP + k] = v;
        }
        __syncthreads();
        const int n = node0 + ln;
        float4 acc = bv;
        const float* xrow = &Xs[ln * XP];
        #pragma unroll 8
        for (int k = 0; k < K; ++k) {
            float f = xrow[k];
            float4 w = *(const float4*)&Ws[k * C + c0];
            acc.x += f * w.x;
            acc.y += f * w.y;
            acc.z += f * w.z;
            acc.w += f * w.w;
        }
        if (n < N_NODES) *(float4*)&Y[(size_t)n * C + c0] = acc;
    }
}

// ---------------------------------------------------------------- scatter
// agg[dst] += h[src] * dinv[src]*dinv[dst], float4 per thread
template<int C>
__global__ __launch_bounds__(256) void k_scatter(const float* __restrict__ h,
                                                 const int* __restrict__ src,
                                                 const int* __restrict__ dst,
                                                 const float* __restrict__ dinv,
                                                 float* __restrict__ agg) {
    constexpr int G = C / 4;  // threads per edge
    int gid = blockIdx.x * 256 + threadIdx.x;
    int e = gid / G;
    int c0 = (gid % G) * 4;
    if (e < N_EDGES) {
        int s = src[e], d = dst[e];
        float norm = dinv[s] * dinv[d];
        float4 v = *(const float4*)&h[(size_t)s * C + c0];
        float* ap = &agg[(size_t)d * C + c0];
        atomicAdd(ap + 0, v.x * norm);
        atomicAdd(ap + 1, v.y * norm);
        atomicAdd(ap + 2, v.z * norm);
        atomicAdd(ap + 3, v.w * norm);
    }
}

// ---------------------------------------------------------------- mix + BN stats
// x = gamma*agg + (1-gamma)*h, stored back into agg; per-channel sum/sumsq.
template<int C>
__global__ __launch_bounds__(256) void k_mix_bn(const float* __restrict__ h,
                                                float* __restrict__ agg,
                                                const float* __restrict__ gammaP,
                                                int r,
                                                float* __restrict__ bnsum,
                                                float* __restrict__ bnsq,
                                                int nodesPerBlock) {
    constexpr int NSUB = 256 / C;
    const float g = gammaP[r];
    const float gi = 1.0f - g;
    const int tid = threadIdx.x;
    const int c = tid % C;
    const int sub = tid / C;
    const int nodeStart = blockIdx.x * nodesPerBlock;
    float s = 0.0f, sq = 0.0f;
    for (int n = nodeStart + sub; n < nodeStart + nodesPerBlock; n += NSUB) {
        if (n < N_NODES) {
            size_t idx = (size_t)n * C + c;
            float x = g * agg[idx] + gi * h[idx];
            agg[idx] = x;
            s += x;
            sq += x * x;
        }
    }
    __shared__ float red[256];
    red[tid] = s;
    __syncthreads();
    if (sub == 0) {
        float t = 0.0f;
        #pragma unroll
        for (int i = 0; i < NSUB; ++i) t += red[c + i * C];
        atomicAdd(&bnsum[c], t);
    }
    __syncthreads();
    red[tid] = sq;
    __syncthreads();
    if (sub == 0) {
        float t = 0.0f;
        #pragma unroll
        for (int i = 0; i < NSUB; ++i) t += red[c + i * C];
        atomicAdd(&bnsq[c], t);
    }
}

// ---------------------------------------------------------------- BN finalize
template<int C>
__global__ void k_bnfin(const float* __restrict__ bnsum,
                        const float* __restrict__ bnsq,
                        const float* __restrict__ scale,
                        const float* __restrict__ bias,
                        float* __restrict__ se, float* __restrict__ be) {
    int c = threadIdx.x;
    if (c < C) {
        float m = bnsum[c] * (1.0f / N_NODES);
        float v = bnsq[c] * (1.0f / N_NODES) - m * m;
        float inv = rsqrtf(v + BN_EPS);
        float sc = inv * scale[c];
        se[c] = sc;
        be[c] = bias[c] - m * sc;
    }
}

// ---------------------------------------------------------------- output
// y = relu(bn2(x2[batch])), log_softmax over 32 channels, write [B, R*32]
__global__ __launch_bounds__(256) void k_out(const float* __restrict__ x2,
                                             const int* __restrict__ batch,
                                             const float* __restrict__ se,
                                             const float* __restrict__ be,
                                             float* __restrict__ out, int r) {
    int gid = blockIdx.x * 256 + threadIdx.x;
    int b = gid >> 5;
    int c = gid & 31;
    if (b < B_NODES) {
        int node = batch[b];
        float y = fmaxf(x2[(size_t)node * 32 + c] * se[c] + be[c], 0.0f);
        float m = y;
        #pragma unroll
        for (int off = 16; off; off >>= 1) m = fmaxf(m, __shfl_xor(m, off, 32));
        float ex = __expf(y - m);
        float ssum = ex;
        #pragma unroll
        for (int off = 16; off; off >>= 1) ssum += __shfl_xor(ssum, off, 32);
        out[(size_t)b * (N_REL * 32) + r * 32 + c] = (y - m) - __logf(ssum);
    }
}

// ---------------------------------------------------------------- launcher
extern "C" void kernel_launch(void* const* d_in, const int* in_sizes, int n_in,
                              void* d_out, int out_size, void* d_ws, size_t ws_size,
                              hipStream_t stream) {
    const float* features   = (const float*)d_in[0];
    const int*   edge_index = (const int*)d_in[1];
    const int*   batch_nodes= (const int*)d_in[2];
    const float* W1         = (const float*)d_in[3];
    const float* b1         = (const float*)d_in[4];
    const float* W2         = (const float*)d_in[5];
    const float* b2         = (const float*)d_in[6];
    const float* gamma1     = (const float*)d_in[7];
    const float* gamma2     = (const float*)d_in[8];
    const float* bn1_scale  = (const float*)d_in[9];
    const float* bn1_bias   = (const float*)d_in[10];
    const float* bn2_scale  = (const float*)d_in[11];
    const float* bn2_bias   = (const float*)d_in[12];
    float* out = (float*)d_out;
    float* ws  = (float*)d_ws;

    // workspace layout (floats); zero-region first so one memset covers it
    size_t off = 0;
    float* deg    = ws + off; off += N_NODES;               // becomes dinv
    float* agg1   = ws + off; off += (size_t)N_NODES * 64;  // becomes x1
    float* agg2   = ws + off; off += (size_t)N_NODES * 32;  // becomes x2
    float* bnsum1 = ws + off; off += 64;
    float* bnsq1  = ws + off; off += 64;
    float* bnsum2 = ws + off; off += 32;
    float* bnsq2  = ws + off; off += 32;
    const size_t zeroFloats = off;
    float* se1 = ws + off; off += 64;
    float* be1 = ws + off; off += 64;
    float* se2 = ws + off; off += 32;
    float* be2 = ws + off; off += 32;
    float* h1  = ws + off; off += (size_t)N_NODES * 64;
    float* h2  = ws + off; off += (size_t)N_NODES * 32;

    for (int r = 0; r < N_REL; ++r) {
        const int* src = edge_index + (size_t)r * 2 * N_EDGES;
        const int* dst = src + N_EDGES;

        hipMemsetAsync(ws, 0, zeroFloats * sizeof(float), stream);

        k_deg<<<(N_EDGES + 255) / 256, 256, 0, stream>>>(dst, deg);
        k_dinv<<<(N_NODES + 255) / 256, 256, 0, stream>>>(deg);

        // conv1: h1 = feat @ W1[r] + b1[r]
        k_gemm<128, 64, false><<<(N_NODES + 63) / 64, 256, 0, stream>>>(
            features, W1 + (size_t)r * 128 * 64, b1 + r * 64,
            nullptr, nullptr, h1, 64);

        k_scatter<64><<<(int)(((size_t)N_EDGES * 16 + 255) / 256), 256, 0, stream>>>(
            h1, src, dst, deg, agg1);

        k_mix_bn<64><<<(N_NODES + 255) / 256, 256, 0, stream>>>(
            h1, agg1, gamma1, r, bnsum1, bnsq1, 256);
        k_bnfin<64><<<1, 64, 0, stream>>>(bnsum1, bnsq1,
            bn1_scale + r * 64, bn1_bias + r * 64, se1, be1);

        // conv2: h2 = relu(bn1(x1)) @ W2[r] + b2[r]   (BN+relu fused in load)
        k_gemm<64, 32, true><<<(N_NODES + 127) / 128, 256, 0, stream>>>(
            agg1, W2 + (size_t)r * 64 * 32, b2 + r * 32, se1, be1, h2, 128);

        k_scatter<32><<<(int)(((size_t)N_EDGES * 8 + 255) / 256), 256, 0, stream>>>(
            h2, src, dst, deg, agg2);

        k_mix_bn<32><<<(N_NODES + 255) / 256, 256, 0, stream>>>(
            h2, agg2, gamma2, r, bnsum2, bnsq2, 256);
        k_bnfin<32><<<1, 32, 0, stream>>>(bnsum2, bnsq2,
            bn2_scale + r * 32, bn2_bias + r * 32, se2, be2);

        k_out<<<(B_NODES * 32 + 255) / 256, 256, 0, stream>>>(
            agg2, batch_nodes, se2, be2, out, r);
    }
}

// Round 2
// 1889.665 us; speedup vs baseline: 3.5160x; 3.5160x over previous
//
#include <hip/hip_runtime.h>
#include <math.h>

#define N_NODES 100000
#define N_PAD   100352   // 98 * 1024, for the scan kernels
#define N_EDGES 1600000
#define N_REL   3
#define F_DIM   128
#define H_DIM   64
#define O_DIM   32
#define B_NODES 50000
#define BN_EPS  1e-5f

// ---------------------------------------------------------------- degree (int)
__global__ __launch_bounds__(256) void k_deg(const int* __restrict__ dst,
                                             int* __restrict__ deg) {
    int e = blockIdx.x * 256 + threadIdx.x;
    if (e < N_EDGES) atomicAdd(&deg[dst[e]], 1);
}

__global__ __launch_bounds__(256) void k_dinv(const int* __restrict__ deg,
                                              float* __restrict__ dinv) {
    int n = blockIdx.x * 256 + threadIdx.x;
    if (n < N_NODES) dinv[n] = rsqrtf(fmaxf((float)deg[n], 1.0f));
}

// ---------------------------------------------------------------- scan phase A
// blockSums[b] = sum of deg over 1024-element range (int4 loads, no guards:
// deg is padded/zeroed to N_PAD)
__global__ __launch_bounds__(256) void k_blocksum(const int* __restrict__ deg,
                                                  int* __restrict__ blockSums) {
    const int t = threadIdx.x;
    const int4 d4 = ((const int4*)deg)[blockIdx.x * 256 + t];
    int lsum = d4.x + d4.y + d4.z + d4.w;
    __shared__ int sh[256];
    sh[t] = lsum;
    __syncthreads();
    for (int o = 128; o > 0; o >>= 1) {
        if (t < o) sh[t] += sh[t + o];
        __syncthreads();
    }
    if (t == 0) blockSums[blockIdx.x] = sh[0];
}

// ---------------------------------------------------------------- scan phase B
// exclusive scan of 98 block sums in one block; also writes rowptr[N] = E
__global__ void k_scanoff(const int* __restrict__ blockSums,
                          int* __restrict__ blockOff,
                          int* __restrict__ rowptr, int nb) {
    __shared__ int sh[128];
    const int t = threadIdx.x;
    int v = (t < nb) ? blockSums[t] : 0;
    sh[t] = v;
    __syncthreads();
    for (int o = 1; o < 128; o <<= 1) {
        int add = (t >= o) ? sh[t - o] : 0;
        __syncthreads();
        sh[t] += add;
        __syncthreads();
    }
    if (t < nb) blockOff[t] = sh[t] - v;
    if (t == 0) rowptr[N_NODES] = N_EDGES;
}

// ---------------------------------------------------------------- scan phase C
// full exclusive scan: rowptr[i] for i in [0, N_PAD)
__global__ __launch_bounds__(256) void k_scan2(const int* __restrict__ deg,
                                               const int* __restrict__ blockOff,
                                               int* __restrict__ rowptr) {
    const int t = threadIdx.x;
    const int gi = blockIdx.x * 256 + t;
    const int4 d4 = ((const int4*)deg)[gi];
    const int lsum = d4.x + d4.y + d4.z + d4.w;
    __shared__ int sh[256];
    sh[t] = lsum;
    __syncthreads();
    for (int o = 1; o < 256; o <<= 1) {
        int add = (t >= o) ? sh[t - o] : 0;
        __syncthreads();
        sh[t] += add;
        __syncthreads();
    }
    int base = blockOff[blockIdx.x] + sh[t] - lsum;
    int i0 = gi * 4;
    rowptr[i0 + 0] = base;
    rowptr[i0 + 1] = base + d4.x;
    rowptr[i0 + 2] = base + d4.x + d4.y;
    rowptr[i0 + 3] = base + d4.x + d4.y + d4.z;
}

// ---------------------------------------------------------------- bucket edges
// edat[pos] = {src, norm} sorted by dst segment
__global__ __launch_bounds__(256) void k_bucket(const int* __restrict__ src,
                                                const int* __restrict__ dst,
                                                const float* __restrict__ dinv,
                                                const int* __restrict__ rowptr,
                                                int* __restrict__ cursor,
                                                int2* __restrict__ edat) {
    int e = blockIdx.x * 256 + threadIdx.x;
    if (e < N_EDGES) {
        int s = src[e], d = dst[e];
        float w = dinv[s] * dinv[d];
        int pos = rowptr[d] + atomicAdd(&cursor[d], 1);
        edat[pos] = make_int2(s, __float_as_int(w));
    }
}

// ---------------------------------------------------------------- GEMM
// Y[n][c] = bias[c] + sum_k X[n][k] * W[k][c]; optional fused BN+relu on X.
template<int K, int C, bool BN>
__global__ __launch_bounds__(256) void k_gemm(const float* __restrict__ X,
                                              const float* __restrict__ W,
                                              const float* __restrict__ bias,
                                              const float* __restrict__ se,
                                              const float* __restrict__ be,
                                              float* __restrict__ Y,
                                              int nodesPerBlock) {
    constexpr int CG = C / 4;
    constexpr int NPASS = 256 / CG;
    constexpr int XP = K + 1;
    __shared__ __align__(16) float Ws[K * C];
    __shared__ float Xs[NPASS * XP];
    const int tid = threadIdx.x;
    for (int i = tid; i < K * C; i += 256) Ws[i] = W[i];
    const int cg = tid % CG;
    const int ln = tid / CG;
    const int c0 = cg * 4;
    const float4 bv = *(const float4*)&bias[c0];
    const int blockStart = blockIdx.x * nodesPerBlock;
    const int passes = nodesPerBlock / NPASS;
    for (int p = 0; p < passes; ++p) {
        const int node0 = blockStart + p * NPASS;
        __syncthreads();
        for (int i = tid; i < NPASS * K; i += 256) {
            int lnn = i / K, k = i % K;
            int n = node0 + lnn;
            float v = 0.0f;
            if (n < N_NODES) {
                v = X[(size_t)n * K + k];
                if (BN) v = fmaxf(v * se[k] + be[k], 0.0f);
            }
            Xs[lnn * XP + k] = v;
        }
        __syncthreads();
        const int n = node0 + ln;
        float4 acc = bv;
        const float* xrow = &Xs[ln * XP];
        #pragma unroll 8
        for (int k = 0; k < K; ++k) {
            float f = xrow[k];
            float4 w = *(const float4*)&Ws[k * C + c0];
            acc.x += f * w.x;
            acc.y += f * w.y;
            acc.z += f * w.z;
            acc.w += f * w.w;
        }
        if (n < N_NODES) *(float4*)&Y[(size_t)n * C + c0] = acc;
    }
}

// ---------------------------------------------------------------- gather-agg
// One C-lane slot per dst node: acc over CSR segment, fused gamma-mix + BN
// partial stats. X[n][c] = g*agg + (1-g)*h[n][c].
template<int C>
__global__ __launch_bounds__(256) void k_gather(const float* __restrict__ h,
                                                const int* __restrict__ rowptr,
                                                const int2* __restrict__ edat,
                                                const float* __restrict__ gammaP,
                                                int r, int npb,
                                                float* __restrict__ X,
                                                float* __restrict__ bnsum,
                                                float* __restrict__ bnsq) {
    constexpr int WPB = 256 / C;   // node slots per block
    const int c = threadIdx.x % C;
    const int slot = threadIdx.x / C;
    const float g = gammaP[r];
    const float gi = 1.0f - g;
    const int n0 = blockIdx.x * npb;
    float s = 0.0f, sq = 0.0f;
    for (int i = slot; i < npb; i += WPB) {
        int n = n0 + i;
        if (n >= N_NODES) break;
        int rs = rowptr[n], re = rowptr[n + 1];
        float acc = 0.0f;
        for (int e = rs; e < re; ++e) {
            int2 ed = edat[e];
            acc += h[(size_t)ed.x * C + c] * __int_as_float(ed.y);
        }
        float x = g * acc + gi * h[(size_t)n * C + c];
        X[(size_t)n * C + c] = x;
        s += x;
        sq += x * x;
    }
    __shared__ float red[256];
    red[threadIdx.x] = s;
    __syncthreads();
    if (slot == 0) {
        float t = 0.0f;
        #pragma unroll
        for (int i = 0; i < WPB; ++i) t += red[c + i * C];
        atomicAdd(&bnsum[c], t);
    }
    __syncthreads();
    red[threadIdx.x] = sq;
    __syncthreads();
    if (slot == 0) {
        float t = 0.0f;
        #pragma unroll
        for (int i = 0; i < WPB; ++i) t += red[c + i * C];
        atomicAdd(&bnsq[c], t);
    }
}

// ---------------------------------------------------------------- BN finalize
template<int C>
__global__ void k_bnfin(const float* __restrict__ bnsum,
                        const float* __restrict__ bnsq,
                        const float* __restrict__ scale,
                        const float* __restrict__ bias,
                        float* __restrict__ se, float* __restrict__ be) {
    int c = threadIdx.x;
    if (c < C) {
        float m = bnsum[c] * (1.0f / N_NODES);
        float v = bnsq[c] * (1.0f / N_NODES) - m * m;
        float inv = rsqrtf(v + BN_EPS);
        float sc = inv * scale[c];
        se[c] = sc;
        be[c] = bias[c] - m * sc;
    }
}

// ---------------------------------------------------------------- output
__global__ __launch_bounds__(256) void k_out(const float* __restrict__ x2,
                                             const int* __restrict__ batch,
                                             const float* __restrict__ se,
                                             const float* __restrict__ be,
                                             float* __restrict__ out, int r) {
    int gid = blockIdx.x * 256 + threadIdx.x;
    int b = gid >> 5;
    int c = gid & 31;
    if (b < B_NODES) {
        int node = batch[b];
        float y = fmaxf(x2[(size_t)node * 32 + c] * se[c] + be[c], 0.0f);
        float m = y;
        #pragma unroll
        for (int off = 16; off; off >>= 1) m = fmaxf(m, __shfl_xor(m, off, 32));
        float ex = __expf(y - m);
        float ssum = ex;
        #pragma unroll
        for (int off = 16; off; off >>= 1) ssum += __shfl_xor(ssum, off, 32);
        out[(size_t)b * (N_REL * 32) + r * 32 + c] = (y - m) - __logf(ssum);
    }
}

// ---------------------------------------------------------------- launcher
extern "C" void kernel_launch(void* const* d_in, const int* in_sizes, int n_in,
                              void* d_out, int out_size, void* d_ws, size_t ws_size,
                              hipStream_t stream) {
    const float* features    = (const float*)d_in[0];
    const int*   edge_index  = (const int*)d_in[1];
    const int*   batch_nodes = (const int*)d_in[2];
    const float* W1          = (const float*)d_in[3];
    const float* b1          = (const float*)d_in[4];
    const float* W2          = (const float*)d_in[5];
    const float* b2          = (const float*)d_in[6];
    const float* gamma1      = (const float*)d_in[7];
    const float* gamma2      = (const float*)d_in[8];
    const float* bn1_scale   = (const float*)d_in[9];
    const float* bn1_bias    = (const float*)d_in[10];
    const float* bn2_scale   = (const float*)d_in[11];
    const float* bn2_bias    = (const float*)d_in[12];
    float* out = (float*)d_out;

    // ---- workspace layout (4-byte units) ----
    // zero-region (one memset/relation): deg (padded) + cursor + bn sums
    char* wsB = (char*)d_ws;
    size_t off = 0;
    int*   deg    = (int*)(wsB + off); off += (size_t)N_PAD * 4;       // padded for int4 scan
    int*   cursor = (int*)(wsB + off); off += (size_t)N_NODES * 4;
    float* bnsum1 = (float*)(wsB + off); off += 64 * 4;
    float* bnsq1  = (float*)(wsB + off); off += 64 * 4;
    float* bnsum2 = (float*)(wsB + off); off += 32 * 4;
    float* bnsq2  = (float*)(wsB + off); off += 32 * 4;
    const size_t zeroBytes = off;
    // non-zeroed scratch
    float* dinv      = (float*)(wsB + off); off += (size_t)N_NODES * 4;
    int*   rowptr    = (int*)(wsB + off); off += (size_t)(N_PAD + 1) * 4;
    int*   blockSums = (int*)(wsB + off); off += 128 * 4;
    int*   blockOff  = (int*)(wsB + off); off += 128 * 4;
    float* se1 = (float*)(wsB + off); off += 64 * 4;
    float* be1 = (float*)(wsB + off); off += 64 * 4;
    float* se2 = (float*)(wsB + off); off += 32 * 4;
    float* be2 = (float*)(wsB + off); off += 32 * 4;
    int2*  edat = (int2*)(wsB + off); off += (size_t)N_EDGES * 8;
    float* h1   = (float*)(wsB + off); off += (size_t)N_NODES * 64 * 4;
    float* x1   = (float*)(wsB + off); off += (size_t)N_NODES * 64 * 4;
    float* h2   = (float*)(wsB + off); off += (size_t)N_NODES * 32 * 4;
    float* x2   = h1;  // alias: h1 dead after gather<64>, x2 live gather<32>..k_out

    const int nScanBlocks = N_PAD / 1024;  // 98

    for (int r = 0; r < N_REL; ++r) {
        const int* src = edge_index + (size_t)r * 2 * N_EDGES;
        const int* dst = src + N_EDGES;

        hipMemsetAsync(d_ws, 0, zeroBytes, stream);

        // ---- CSR build (reused by both convs) ----
        k_deg<<<(N_EDGES + 255) / 256, 256, 0, stream>>>(dst, deg);
        k_dinv<<<(N_NODES + 255) / 256, 256, 0, stream>>>(deg, dinv);
        k_blocksum<<<nScanBlocks, 256, 0, stream>>>(deg, blockSums);
        k_scanoff<<<1, 128, 0, stream>>>(blockSums, blockOff, rowptr, nScanBlocks);
        k_scan2<<<nScanBlocks, 256, 0, stream>>>(deg, blockOff, rowptr);
        k_bucket<<<(N_EDGES + 255) / 256, 256, 0, stream>>>(src, dst, dinv,
                                                            rowptr, cursor, edat);

        // ---- conv1 ----
        k_gemm<128, 64, false><<<(N_NODES + 63) / 64, 256, 0, stream>>>(
            features, W1 + (size_t)r * 128 * 64, b1 + r * 64,
            nullptr, nullptr, h1, 64);
        k_gather<64><<<(N_NODES + 31) / 32, 256, 0, stream>>>(
            h1, rowptr, edat, gamma1, r, 32, x1, bnsum1, bnsq1);
        k_bnfin<64><<<1, 64, 0, stream>>>(bnsum1, bnsq1,
            bn1_scale + r * 64, bn1_bias + r * 64, se1, be1);

        // ---- conv2 (BN+relu fused into GEMM load) ----
        k_gemm<64, 32, true><<<(N_NODES + 127) / 128, 256, 0, stream>>>(
            x1, W2 + (size_t)r * 64 * 32, b2 + r * 32, se1, be1, h2, 128);
        k_gather<32><<<(N_NODES + 63) / 64, 256, 0, stream>>>(
            h2, rowptr, edat, gamma2, r, 64, x2, bnsum2, bnsq2);
        k_bnfin<32><<<1, 32, 0, stream>>>(bnsum2, bnsq2,
            bn2_scale + r * 32, bn2_bias + r * 32, se2, be2);

        // ---- output ----
        k_out<<<(B_NODES * 32 + 255) / 256, 256, 0, stream>>>(
            x2, batch_nodes, se2, be2, out, r);
    }
}

// Round 3
// 1521.903 us; speedup vs baseline: 4.3656x; 1.2416x over previous
//
#include <hip/hip_runtime.h>
#include <math.h>

#define N_NODES 100000
#define N_PAD   100352   // 98 * 1024, for the scan kernels
#define N_EDGES 1600000
#define N_REL   3
#define F_DIM   128
#define H_DIM   64
#define O_DIM   32
#define B_NODES 50000
#define BN_EPS  1e-5f

// ---------------------------------------------------------------- degree (int)
__global__ __launch_bounds__(256) void k_deg(const int* __restrict__ dst,
                                             int* __restrict__ deg) {
    int e = blockIdx.x * 256 + threadIdx.x;
    if (e < N_EDGES) atomicAdd(&deg[dst[e]], 1);
}

__global__ __launch_bounds__(256) void k_dinv(const int* __restrict__ deg,
                                              float* __restrict__ dinv) {
    int n = blockIdx.x * 256 + threadIdx.x;
    if (n < N_NODES) dinv[n] = rsqrtf(fmaxf((float)deg[n], 1.0f));
}

// ---------------------------------------------------------------- scan phase A
__global__ __launch_bounds__(256) void k_blocksum(const int* __restrict__ deg,
                                                  int* __restrict__ blockSums) {
    const int t = threadIdx.x;
    const int4 d4 = ((const int4*)deg)[blockIdx.x * 256 + t];
    int lsum = d4.x + d4.y + d4.z + d4.w;
    __shared__ int sh[256];
    sh[t] = lsum;
    __syncthreads();
    for (int o = 128; o > 0; o >>= 1) {
        if (t < o) sh[t] += sh[t + o];
        __syncthreads();
    }
    if (t == 0) blockSums[blockIdx.x] = sh[0];
}

// ---------------------------------------------------------------- scan phase B
__global__ void k_scanoff(const int* __restrict__ blockSums,
                          int* __restrict__ blockOff,
                          int* __restrict__ rowptr, int nb) {
    __shared__ int sh[128];
    const int t = threadIdx.x;
    int v = (t < nb) ? blockSums[t] : 0;
    sh[t] = v;
    __syncthreads();
    for (int o = 1; o < 128; o <<= 1) {
        int add = (t >= o) ? sh[t - o] : 0;
        __syncthreads();
        sh[t] += add;
        __syncthreads();
    }
    if (t < nb) blockOff[t] = sh[t] - v;
    if (t == 0) rowptr[N_NODES] = N_EDGES;
}

// ---------------------------------------------------------------- scan phase C
__global__ __launch_bounds__(256) void k_scan2(const int* __restrict__ deg,
                                               const int* __restrict__ blockOff,
                                               int* __restrict__ rowptr) {
    const int t = threadIdx.x;
    const int gi = blockIdx.x * 256 + t;
    const int4 d4 = ((const int4*)deg)[gi];
    const int lsum = d4.x + d4.y + d4.z + d4.w;
    __shared__ int sh[256];
    sh[t] = lsum;
    __syncthreads();
    for (int o = 1; o < 256; o <<= 1) {
        int add = (t >= o) ? sh[t - o] : 0;
        __syncthreads();
        sh[t] += add;
        __syncthreads();
    }
    int base = blockOff[blockIdx.x] + sh[t] - lsum;
    int i0 = gi * 4;
    rowptr[i0 + 0] = base;
    rowptr[i0 + 1] = base + d4.x;
    rowptr[i0 + 2] = base + d4.x + d4.y;
    rowptr[i0 + 3] = base + d4.x + d4.y + d4.z;
}

// ---------------------------------------------------------------- bucket edges
__global__ __launch_bounds__(256) void k_bucket(const int* __restrict__ src,
                                                const int* __restrict__ dst,
                                                const float* __restrict__ dinv,
                                                const int* __restrict__ rowptr,
                                                int* __restrict__ cursor,
                                                int2* __restrict__ edat) {
    int e = blockIdx.x * 256 + threadIdx.x;
    if (e < N_EDGES) {
        int s = src[e], d = dst[e];
        float w = dinv[s] * dinv[d];
        int pos = rowptr[d] + atomicAdd(&cursor[d], 1);
        edat[pos] = make_int2(s, __float_as_int(w));
    }
}

// ---------------------------------------------------------------- GEMM
template<int K, int C, bool BN>
__global__ __launch_bounds__(256) void k_gemm(const float* __restrict__ X,
                                              const float* __restrict__ W,
                                              const float* __restrict__ bias,
                                              const float* __restrict__ se,
                                              const float* __restrict__ be,
                                              float* __restrict__ Y,
                                              int nodesPerBlock) {
    constexpr int CG = C / 4;
    constexpr int NPASS = 256 / CG;
    constexpr int XP = K + 1;
    __shared__ __align__(16) float Ws[K * C];
    __shared__ float Xs[NPASS * XP];
    const int tid = threadIdx.x;
    for (int i = tid; i < K * C; i += 256) Ws[i] = W[i];
    const int cg = tid % CG;
    const int ln = tid / CG;
    const int c0 = cg * 4;
    const float4 bv = *(const float4*)&bias[c0];
    const int blockStart = blockIdx.x * nodesPerBlock;
    const int passes = nodesPerBlock / NPASS;
    for (int p = 0; p < passes; ++p) {
        const int node0 = blockStart + p * NPASS;
        __syncthreads();
        for (int i = tid; i < NPASS * K; i += 256) {
            int lnn = i / K, k = i % K;
            int n = node0 + lnn;
            float v = 0.0f;
            if (n < N_NODES) {
                v = X[(size_t)n * K + k];
                if (BN) v = fmaxf(v * se[k] + be[k], 0.0f);
            }
            Xs[lnn * XP + k] = v;
        }
        __syncthreads();
        const int n = node0 + ln;
        float4 acc = bv;
        const float* xrow = &Xs[ln * XP];
        #pragma unroll 8
        for (int k = 0; k < K; ++k) {
            float f = xrow[k];
            float4 w = *(const float4*)&Ws[k * C + c0];
            acc.x += f * w.x;
            acc.y += f * w.y;
            acc.z += f * w.z;
            acc.w += f * w.w;
        }
        if (n < N_NODES) *(float4*)&Y[(size_t)n * C + c0] = acc;
    }
}

// ---------------------------------------------------------------- gather-agg
// 4-wide edge unroll: 4 independent edat loads then 4 independent h-row
// gathers in flight per wave (latency-bound -> bandwidth-bound).
template<int C>
__global__ __launch_bounds__(256) void k_gather(const float* __restrict__ h,
                                                const int* __restrict__ rowptr,
                                                const int2* __restrict__ edat,
                                                const float* __restrict__ gammaP,
                                                int r, int npb,
                                                float* __restrict__ X,
                                                float* __restrict__ bnsum,
                                                float* __restrict__ bnsq) {
    constexpr int WPB = 256 / C;   // node slots per block
    const int c = threadIdx.x % C;
    const int slot = threadIdx.x / C;
    const float g = gammaP[r];
    const float gi = 1.0f - g;
    const int n0 = blockIdx.x * npb;
    float s = 0.0f, sq = 0.0f;
    for (int i = slot; i < npb; i += WPB) {
        int n = n0 + i;
        if (n >= N_NODES) break;
        int rs = rowptr[n], re = rowptr[n + 1];
        float acc = 0.0f;
        int e = rs;
        for (; e + 4 <= re; e += 4) {
            int2 e0 = edat[e + 0];
            int2 e1 = edat[e + 1];
            int2 e2 = edat[e + 2];
            int2 e3 = edat[e + 3];
            float v0 = h[(size_t)e0.x * C + c];
            float v1 = h[(size_t)e1.x * C + c];
            float v2 = h[(size_t)e2.x * C + c];
            float v3 = h[(size_t)e3.x * C + c];
            acc += v0 * __int_as_float(e0.y);
            acc += v1 * __int_as_float(e1.y);
            acc += v2 * __int_as_float(e2.y);
            acc += v3 * __int_as_float(e3.y);
        }
        for (; e < re; ++e) {
            int2 ed = edat[e];
            acc += h[(size_t)ed.x * C + c] * __int_as_float(ed.y);
        }
        float x = g * acc + gi * h[(size_t)n * C + c];
        X[(size_t)n * C + c] = x;
        s += x;
        sq += x * x;
    }
    __shared__ float red[256];
    red[threadIdx.x] = s;
    __syncthreads();
    if (slot == 0) {
        float t = 0.0f;
        #pragma unroll
        for (int i = 0; i < WPB; ++i) t += red[c + i * C];
        atomicAdd(&bnsum[c], t);
    }
    __syncthreads();
    red[threadIdx.x] = sq;
    __syncthreads();
    if (slot == 0) {
        float t = 0.0f;
        #pragma unroll
        for (int i = 0; i < WPB; ++i) t += red[c + i * C];
        atomicAdd(&bnsq[c], t);
    }
}

// ---------------------------------------------------------------- BN finalize
template<int C>
__global__ void k_bnfin(const float* __restrict__ bnsum,
                        const float* __restrict__ bnsq,
                        const float* __restrict__ scale,
                        const float* __restrict__ bias,
                        float* __restrict__ se, float* __restrict__ be) {
    int c = threadIdx.x;
    if (c < C) {
        float m = bnsum[c] * (1.0f / N_NODES);
        float v = bnsq[c] * (1.0f / N_NODES) - m * m;
        float inv = rsqrtf(v + BN_EPS);
        float sc = inv * scale[c];
        se[c] = sc;
        be[c] = bias[c] - m * sc;
    }
}

// ---------------------------------------------------------------- output
__global__ __launch_bounds__(256) void k_out(const float* __restrict__ x2,
                                             const int* __restrict__ batch,
                                             const float* __restrict__ se,
                                             const float* __restrict__ be,
                                             float* __restrict__ out, int r) {
    int gid = blockIdx.x * 256 + threadIdx.x;
    int b = gid >> 5;
    int c = gid & 31;
    if (b < B_NODES) {
        int node = batch[b];
        float y = fmaxf(x2[(size_t)node * 32 + c] * se[c] + be[c], 0.0f);
        float m = y;
        #pragma unroll
        for (int off = 16; off; off >>= 1) m = fmaxf(m, __shfl_xor(m, off, 32));
        float ex = __expf(y - m);
        float ssum = ex;
        #pragma unroll
        for (int off = 16; off; off >>= 1) ssum += __shfl_xor(ssum, off, 32);
        out[(size_t)b * (N_REL * 32) + r * 32 + c] = (y - m) - __logf(ssum);
    }
}

// ---------------------------------------------------------------- launcher
extern "C" void kernel_launch(void* const* d_in, const int* in_sizes, int n_in,
                              void* d_out, int out_size, void* d_ws, size_t ws_size,
                              hipStream_t stream) {
    const float* features    = (const float*)d_in[0];
    const int*   edge_index  = (const int*)d_in[1];
    const int*   batch_nodes = (const int*)d_in[2];
    const float* W1          = (const float*)d_in[3];
    const float* b1          = (const float*)d_in[4];
    const float* W2          = (const float*)d_in[5];
    const float* b2          = (const float*)d_in[6];
    const float* gamma1      = (const float*)d_in[7];
    const float* gamma2      = (const float*)d_in[8];
    const float* bn1_scale   = (const float*)d_in[9];
    const float* bn1_bias    = (const float*)d_in[10];
    const float* bn2_scale   = (const float*)d_in[11];
    const float* bn2_bias    = (const float*)d_in[12];
    float* out = (float*)d_out;

    // ---- workspace layout (4-byte units) ----
    char* wsB = (char*)d_ws;
    size_t off = 0;
    int*   deg    = (int*)(wsB + off); off += (size_t)N_PAD * 4;
    int*   cursor = (int*)(wsB + off); off += (size_t)N_NODES * 4;
    float* bnsum1 = (float*)(wsB + off); off += 64 * 4;
    float* bnsq1  = (float*)(wsB + off); off += 64 * 4;
    float* bnsum2 = (float*)(wsB + off); off += 32 * 4;
    float* bnsq2  = (float*)(wsB + off); off += 32 * 4;
    const size_t zeroBytes = off;
    float* dinv      = (float*)(wsB + off); off += (size_t)N_NODES * 4;
    int*   rowptr    = (int*)(wsB + off); off += (size_t)(N_PAD + 1) * 4;
    int*   blockSums = (int*)(wsB + off); off += 128 * 4;
    int*   blockOff  = (int*)(wsB + off); off += 128 * 4;
    float* se1 = (float*)(wsB + off); off += 64 * 4;
    float* be1 = (float*)(wsB + off); off += 64 * 4;
    float* se2 = (float*)(wsB + off); off += 32 * 4;
    float* be2 = (float*)(wsB + off); off += 32 * 4;
    int2*  edat = (int2*)(wsB + off); off += (size_t)N_EDGES * 8;
    float* h1   = (float*)(wsB + off); off += (size_t)N_NODES * 64 * 4;
    float* x1   = (float*)(wsB + off); off += (size_t)N_NODES * 64 * 4;
    float* h2   = (float*)(wsB + off); off += (size_t)N_NODES * 32 * 4;
    float* x2   = h1;  // alias: h1 dead after gather<64>

    const int nScanBlocks = N_PAD / 1024;  // 98

    for (int r = 0; r < N_REL; ++r) {
        const int* src = edge_index + (size_t)r * 2 * N_EDGES;
        const int* dst = src + N_EDGES;

        hipMemsetAsync(d_ws, 0, zeroBytes, stream);

        // ---- CSR build (reused by both convs) ----
        k_deg<<<(N_EDGES + 255) / 256, 256, 0, stream>>>(dst, deg);
        k_dinv<<<(N_NODES + 255) / 256, 256, 0, stream>>>(deg, dinv);
        k_blocksum<<<nScanBlocks, 256, 0, stream>>>(deg, blockSums);
        k_scanoff<<<1, 128, 0, stream>>>(blockSums, blockOff, rowptr, nScanBlocks);
        k_scan2<<<nScanBlocks, 256, 0, stream>>>(deg, blockOff, rowptr);
        k_bucket<<<(N_EDGES + 255) / 256, 256, 0, stream>>>(src, dst, dinv,
                                                            rowptr, cursor, edat);

        // ---- conv1 ----
        k_gemm<128, 64, false><<<(N_NODES + 63) / 64, 256, 0, stream>>>(
            features, W1 + (size_t)r * 128 * 64, b1 + r * 64,
            nullptr, nullptr, h1, 64);
        k_gather<64><<<(N_NODES + 31) / 32, 256, 0, stream>>>(
            h1, rowptr, edat, gamma1, r, 32, x1, bnsum1, bnsq1);
        k_bnfin<64><<<1, 64, 0, stream>>>(bnsum1, bnsq1,
            bn1_scale + r * 64, bn1_bias + r * 64, se1, be1);

        // ---- conv2 (BN+relu fused into GEMM load) ----
        k_gemm<64, 32, true><<<(N_NODES + 127) / 128, 256, 0, stream>>>(
            x1, W2 + (size_t)r * 64 * 32, b2 + r * 32, se1, be1, h2, 128);
        k_gather<32><<<(N_NODES + 63) / 64, 256, 0, stream>>>(
            h2, rowptr, edat, gamma2, r, 64, x2, bnsum2, bnsq2);
        k_bnfin<32><<<1, 32, 0, stream>>>(bnsum2, bnsq2,
            bn2_scale + r * 32, bn2_bias + r * 32, se2, be2);

        // ---- output ----
        k_out<<<(B_NODES * 32 + 255) / 256, 256, 0, stream>>>(
            x2, batch_nodes, se2, be2, out, r);
    }
}

// Round 4
// 1427.513 us; speedup vs baseline: 4.6543x; 1.0661x over previous
//
#include <hip/hip_runtime.h>
#include <hip/hip_fp16.h>
#include <math.h>

#define N_NODES 100000
#define N_PAD   100352   // 98 * 1024, for the scan kernels
#define N_EDGES 1600000
#define N_REL   3
#define F_DIM   128
#define H_DIM   64
#define O_DIM   32
#define B_NODES 50000
#define BN_EPS  1e-5f

// ---------------------------------------------------------------- degree (int)
__global__ __launch_bounds__(256) void k_deg(const int* __restrict__ dst,
                                             int* __restrict__ deg) {
    int e = blockIdx.x * 256 + threadIdx.x;
    if (e < N_EDGES) atomicAdd(&deg[dst[e]], 1);
}

__global__ __launch_bounds__(256) void k_dinv(const int* __restrict__ deg,
                                              float* __restrict__ dinv) {
    int n = blockIdx.x * 256 + threadIdx.x;
    if (n < N_NODES) dinv[n] = rsqrtf(fmaxf((float)deg[n], 1.0f));
}

// ---------------------------------------------------------------- scan phase A
__global__ __launch_bounds__(256) void k_blocksum(const int* __restrict__ deg,
                                                  int* __restrict__ blockSums) {
    const int t = threadIdx.x;
    const int4 d4 = ((const int4*)deg)[blockIdx.x * 256 + t];
    int lsum = d4.x + d4.y + d4.z + d4.w;
    __shared__ int sh[256];
    sh[t] = lsum;
    __syncthreads();
    for (int o = 128; o > 0; o >>= 1) {
        if (t < o) sh[t] += sh[t + o];
        __syncthreads();
    }
    if (t == 0) blockSums[blockIdx.x] = sh[0];
}

// ---------------------------------------------------------------- scan phase B
__global__ void k_scanoff(const int* __restrict__ blockSums,
                          int* __restrict__ blockOff,
                          int* __restrict__ rowptr, int nb) {
    __shared__ int sh[128];
    const int t = threadIdx.x;
    int v = (t < nb) ? blockSums[t] : 0;
    sh[t] = v;
    __syncthreads();
    for (int o = 1; o < 128; o <<= 1) {
        int add = (t >= o) ? sh[t - o] : 0;
        __syncthreads();
        sh[t] += add;
        __syncthreads();
    }
    if (t < nb) blockOff[t] = sh[t] - v;
    if (t == 0) rowptr[N_NODES] = N_EDGES;
}

// ---------------------------------------------------------------- scan phase C
__global__ __launch_bounds__(256) void k_scan2(const int* __restrict__ deg,
                                               const int* __restrict__ blockOff,
                                               int* __restrict__ rowptr) {
    const int t = threadIdx.x;
    const int gi = blockIdx.x * 256 + t;
    const int4 d4 = ((const int4*)deg)[gi];
    const int lsum = d4.x + d4.y + d4.z + d4.w;
    __shared__ int sh[256];
    sh[t] = lsum;
    __syncthreads();
    for (int o = 1; o < 256; o <<= 1) {
        int add = (t >= o) ? sh[t - o] : 0;
        __syncthreads();
        sh[t] += add;
        __syncthreads();
    }
    int base = blockOff[blockIdx.x] + sh[t] - lsum;
    int i0 = gi * 4;
    rowptr[i0 + 0] = base;
    rowptr[i0 + 1] = base + d4.x;
    rowptr[i0 + 2] = base + d4.x + d4.y;
    rowptr[i0 + 3] = base + d4.x + d4.y + d4.z;
}

// ---------------------------------------------------------------- bucket edges
__global__ __launch_bounds__(256) void k_bucket(const int* __restrict__ src,
                                                const int* __restrict__ dst,
                                                const float* __restrict__ dinv,
                                                const int* __restrict__ rowptr,
                                                int* __restrict__ cursor,
                                                int2* __restrict__ edat) {
    int e = blockIdx.x * 256 + threadIdx.x;
    if (e < N_EDGES) {
        int s = src[e], d = dst[e];
        float w = dinv[s] * dinv[d];
        int pos = rowptr[d] + atomicAdd(&cursor[d], 1);
        edat[pos] = make_int2(s, __float_as_int(w));
    }
}

// ---------------------------------------------------------------- GEMM
// Y[n][c] = bias[c] + sum_k X[n][k] * W[k][c]; fp32 math, fp16 output.
template<int K, int C, bool BN>
__global__ __launch_bounds__(256) void k_gemm(const float* __restrict__ X,
                                              const float* __restrict__ W,
                                              const float* __restrict__ bias,
                                              const float* __restrict__ se,
                                              const float* __restrict__ be,
                                              __half* __restrict__ Y,
                                              int nodesPerBlock) {
    constexpr int CG = C / 4;
    constexpr int NPASS = 256 / CG;
    constexpr int XP = K + 1;
    __shared__ __align__(16) float Ws[K * C];
    __shared__ float Xs[NPASS * XP];
    const int tid = threadIdx.x;
    for (int i = tid; i < K * C; i += 256) Ws[i] = W[i];
    const int cg = tid % CG;
    const int ln = tid / CG;
    const int c0 = cg * 4;
    const float4 bv = *(const float4*)&bias[c0];
    const int blockStart = blockIdx.x * nodesPerBlock;
    const int passes = nodesPerBlock / NPASS;
    for (int p = 0; p < passes; ++p) {
        const int node0 = blockStart + p * NPASS;
        __syncthreads();
        for (int i = tid; i < NPASS * K; i += 256) {
            int lnn = i / K, k = i % K;
            int n = node0 + lnn;
            float v = 0.0f;
            if (n < N_NODES) {
                v = X[(size_t)n * K + k];
                if (BN) v = fmaxf(v * se[k] + be[k], 0.0f);
            }
            Xs[lnn * XP + k] = v;
        }
        __syncthreads();
        const int n = node0 + ln;
        float4 acc = bv;
        const float* xrow = &Xs[ln * XP];
        #pragma unroll 8
        for (int k = 0; k < K; ++k) {
            float f = xrow[k];
            float4 w = *(const float4*)&Ws[k * C + c0];
            acc.x += f * w.x;
            acc.y += f * w.y;
            acc.z += f * w.z;
            acc.w += f * w.w;
        }
        if (n < N_NODES) {
            ushort4 sv;
            sv.x = __half_as_ushort(__float2half_rn(acc.x));
            sv.y = __half_as_ushort(__float2half_rn(acc.y));
            sv.z = __half_as_ushort(__float2half_rn(acc.z));
            sv.w = __half_as_ushort(__float2half_rn(acc.w));
            *(ushort4*)&Y[(size_t)n * C + c0] = sv;
        }
    }
}

// ---------------------------------------------------------------- gather-agg
// 8-wide clamped edge unroll: always 8 edat loads then 8 independent h-row
// gathers in flight, even on short rows (tail lanes get weight 0, index
// clamped to rs which is valid whenever the loop is entered).
template<int C>
__global__ __launch_bounds__(256) void k_gather(const __half* __restrict__ h,
                                                const int* __restrict__ rowptr,
                                                const int2* __restrict__ edat,
                                                const float* __restrict__ gammaP,
                                                int r, int npb,
                                                float* __restrict__ X,
                                                float* __restrict__ bnsum,
                                                float* __restrict__ bnsq) {
    constexpr int WPB = 256 / C;   // node slots per block
    const int c = threadIdx.x % C;
    const int slot = threadIdx.x / C;
    const float g = gammaP[r];
    const float gi = 1.0f - g;
    const int n0 = blockIdx.x * npb;
    float s = 0.0f, sq = 0.0f;
    for (int i = slot; i < npb; i += WPB) {
        int n = n0 + i;
        if (n >= N_NODES) break;
        int rs = rowptr[n], re = rowptr[n + 1];
        float acc = 0.0f;
        for (int e = rs; e < re; e += 8) {
            int2 ed[8];
            #pragma unroll
            for (int j = 0; j < 8; ++j) {
                int t = e + j;
                ed[j] = edat[(t < re) ? t : rs];
            }
            float v[8];
            #pragma unroll
            for (int j = 0; j < 8; ++j)
                v[j] = __half2float(h[(size_t)ed[j].x * C + c]);
            #pragma unroll
            for (int j = 0; j < 8; ++j) {
                float w = (e + j < re) ? __int_as_float(ed[j].y) : 0.0f;
                acc += v[j] * w;
            }
        }
        float x = g * acc + gi * __half2float(h[(size_t)n * C + c]);
        X[(size_t)n * C + c] = x;
        s += x;
        sq += x * x;
    }
    __shared__ float red[256];
    red[threadIdx.x] = s;
    __syncthreads();
    if (slot == 0) {
        float t = 0.0f;
        #pragma unroll
        for (int i = 0; i < WPB; ++i) t += red[c + i * C];
        atomicAdd(&bnsum[c], t);
    }
    __syncthreads();
    red[threadIdx.x] = sq;
    __syncthreads();
    if (slot == 0) {
        float t = 0.0f;
        #pragma unroll
        for (int i = 0; i < WPB; ++i) t += red[c + i * C];
        atomicAdd(&bnsq[c], t);
    }
}

// ---------------------------------------------------------------- BN finalize
template<int C>
__global__ void k_bnfin(const float* __restrict__ bnsum,
                        const float* __restrict__ bnsq,
                        const float* __restrict__ scale,
                        const float* __restrict__ bias,
                        float* __restrict__ se, float* __restrict__ be) {
    int c = threadIdx.x;
    if (c < C) {
        float m = bnsum[c] * (1.0f / N_NODES);
        float v = bnsq[c] * (1.0f / N_NODES) - m * m;
        float inv = rsqrtf(v + BN_EPS);
        float sc = inv * scale[c];
        se[c] = sc;
        be[c] = bias[c] - m * sc;
    }
}

// ---------------------------------------------------------------- output
__global__ __launch_bounds__(256) void k_out(const float* __restrict__ x2,
                                             const int* __restrict__ batch,
                                             const float* __restrict__ se,
                                             const float* __restrict__ be,
                                             float* __restrict__ out, int r) {
    int gid = blockIdx.x * 256 + threadIdx.x;
    int b = gid >> 5;
    int c = gid & 31;
    if (b < B_NODES) {
        int node = batch[b];
        float y = fmaxf(x2[(size_t)node * 32 + c] * se[c] + be[c], 0.0f);
        float m = y;
        #pragma unroll
        for (int off = 16; off; off >>= 1) m = fmaxf(m, __shfl_xor(m, off, 32));
        float ex = __expf(y - m);
        float ssum = ex;
        #pragma unroll
        for (int off = 16; off; off >>= 1) ssum += __shfl_xor(ssum, off, 32);
        out[(size_t)b * (N_REL * 32) + r * 32 + c] = (y - m) - __logf(ssum);
    }
}

// ---------------------------------------------------------------- launcher
extern "C" void kernel_launch(void* const* d_in, const int* in_sizes, int n_in,
                              void* d_out, int out_size, void* d_ws, size_t ws_size,
                              hipStream_t stream) {
    const float* features    = (const float*)d_in[0];
    const int*   edge_index  = (const int*)d_in[1];
    const int*   batch_nodes = (const int*)d_in[2];
    const float* W1          = (const float*)d_in[3];
    const float* b1          = (const float*)d_in[4];
    const float* W2          = (const float*)d_in[5];
    const float* b2          = (const float*)d_in[6];
    const float* gamma1      = (const float*)d_in[7];
    const float* gamma2      = (const float*)d_in[8];
    const float* bn1_scale   = (const float*)d_in[9];
    const float* bn1_bias    = (const float*)d_in[10];
    const float* bn2_scale   = (const float*)d_in[11];
    const float* bn2_bias    = (const float*)d_in[12];
    float* out = (float*)d_out;

    // ---- workspace layout (byte offsets, 16B aligned) ----
    char* wsB = (char*)d_ws;
    size_t off = 0;
    auto alloc = [&](size_t bytes) {
        void* p = wsB + off;
        off = (off + bytes + 15) & ~(size_t)15;
        return p;
    };
    // zero-region (one memset/relation): deg (padded) + cursor + bn sums
    int*   deg    = (int*)alloc((size_t)N_PAD * 4);
    int*   cursor = (int*)alloc((size_t)N_NODES * 4);
    float* bnsum1 = (float*)alloc(64 * 4);
    float* bnsq1  = (float*)alloc(64 * 4);
    float* bnsum2 = (float*)alloc(32 * 4);
    float* bnsq2  = (float*)alloc(32 * 4);
    const size_t zeroBytes = off;
    // non-zeroed scratch
    float* dinv      = (float*)alloc((size_t)N_NODES * 4);
    int*   rowptr    = (int*)alloc((size_t)(N_PAD + 1) * 4);
    int*   blockSums = (int*)alloc(128 * 4);
    int*   blockOff  = (int*)alloc(128 * 4);
    float* se1 = (float*)alloc(64 * 4);
    float* be1 = (float*)alloc(64 * 4);
    float* se2 = (float*)alloc(32 * 4);
    float* be2 = (float*)alloc(32 * 4);
    int2*   edat = (int2*)alloc((size_t)N_EDGES * 8);
    __half* h1   = (__half*)alloc((size_t)N_NODES * 64 * 2);   // fp16
    float*  x1   = (float*)alloc((size_t)N_NODES * 64 * 4);
    __half* h2   = (__half*)alloc((size_t)N_NODES * 32 * 2);   // fp16
    float*  x2   = (float*)h1;  // alias: h1 (12.8MB) dead after gather<64>; x2 needs 12.8MB

    const int nScanBlocks = N_PAD / 1024;  // 98

    for (int r = 0; r < N_REL; ++r) {
        const int* src = edge_index + (size_t)r * 2 * N_EDGES;
        const int* dst = src + N_EDGES;

        hipMemsetAsync(d_ws, 0, zeroBytes, stream);

        // ---- CSR build (reused by both convs) ----
        k_deg<<<(N_EDGES + 255) / 256, 256, 0, stream>>>(dst, deg);
        k_dinv<<<(N_NODES + 255) / 256, 256, 0, stream>>>(deg, dinv);
        k_blocksum<<<nScanBlocks, 256, 0, stream>>>(deg, blockSums);
        k_scanoff<<<1, 128, 0, stream>>>(blockSums, blockOff, rowptr, nScanBlocks);
        k_scan2<<<nScanBlocks, 256, 0, stream>>>(deg, blockOff, rowptr);
        k_bucket<<<(N_EDGES + 255) / 256, 256, 0, stream>>>(src, dst, dinv,
                                                            rowptr, cursor, edat);

        // ---- conv1 ----
        k_gemm<128, 64, false><<<(N_NODES + 63) / 64, 256, 0, stream>>>(
            features, W1 + (size_t)r * 128 * 64, b1 + r * 64,
            nullptr, nullptr, h1, 64);
        k_gather<64><<<(N_NODES + 31) / 32, 256, 0, stream>>>(
            h1, rowptr, edat, gamma1, r, 32, x1, bnsum1, bnsq1);
        k_bnfin<64><<<1, 64, 0, stream>>>(bnsum1, bnsq1,
            bn1_scale + r * 64, bn1_bias + r * 64, se1, be1);

        // ---- conv2 (BN+relu fused into GEMM load) ----
        k_gemm<64, 32, true><<<(N_NODES + 127) / 128, 256, 0, stream>>>(
            x1, W2 + (size_t)r * 64 * 32, b2 + r * 32, se1, be1, h2, 128);
        k_gather<32><<<(N_NODES + 63) / 64, 256, 0, stream>>>(
            h2, rowptr, edat, gamma2, r, 64, x2, bnsum2, bnsq2);
        k_bnfin<32><<<1, 32, 0, stream>>>(bnsum2, bnsq2,
            bn2_scale + r * 32, bn2_bias + r * 32, se2, be2);

        // ---- output ----
        k_out<<<(B_NODES * 32 + 255) / 256, 256, 0, stream>>>(
            x2, batch_nodes, se2, be2, out, r);
    }
}

// Round 5
// 1400.933 us; speedup vs baseline: 4.7426x; 1.0190x over previous
//
#include <hip/hip_runtime.h>
#include <hip/hip_fp16.h>
#include <math.h>

#define N_NODES 100000
#define N_PAD   100352   // 98 * 1024, for the scan kernels
#define N_EDGES 1600000
#define N_REL   3
#define F_DIM   128
#define H_DIM   64
#define O_DIM   32
#define B_NODES 50000
#define BN_EPS  1e-5f

// ---------------------------------------------------------------- degree (int)
__global__ __launch_bounds__(256) void k_deg(const int* __restrict__ dst,
                                             int* __restrict__ deg) {
    int e = blockIdx.x * 256 + threadIdx.x;
    if (e < N_EDGES) atomicAdd(&deg[dst[e]], 1);
}

__global__ __launch_bounds__(256) void k_dinv(const int* __restrict__ deg,
                                              float* __restrict__ dinv) {
    int n = blockIdx.x * 256 + threadIdx.x;
    if (n < N_NODES) dinv[n] = rsqrtf(fmaxf((float)deg[n], 1.0f));
}

// ---------------------------------------------------------------- scan phase A
__global__ __launch_bounds__(256) void k_blocksum(const int* __restrict__ deg,
                                                  int* __restrict__ blockSums) {
    const int t = threadIdx.x;
    const int4 d4 = ((const int4*)deg)[blockIdx.x * 256 + t];
    int lsum = d4.x + d4.y + d4.z + d4.w;
    __shared__ int sh[256];
    sh[t] = lsum;
    __syncthreads();
    for (int o = 128; o > 0; o >>= 1) {
        if (t < o) sh[t] += sh[t + o];
        __syncthreads();
    }
    if (t == 0) blockSums[blockIdx.x] = sh[0];
}

// ---------------------------------------------------------------- scan phase B
__global__ void k_scanoff(const int* __restrict__ blockSums,
                          int* __restrict__ blockOff,
                          int* __restrict__ rowptr, int nb) {
    __shared__ int sh[128];
    const int t = threadIdx.x;
    int v = (t < nb) ? blockSums[t] : 0;
    sh[t] = v;
    __syncthreads();
    for (int o = 1; o < 128; o <<= 1) {
        int add = (t >= o) ? sh[t - o] : 0;
        __syncthreads();
        sh[t] += add;
        __syncthreads();
    }
    if (t < nb) blockOff[t] = sh[t] - v;
    if (t == 0) rowptr[N_NODES] = N_EDGES;
}

// ---------------------------------------------------------------- scan phase C
__global__ __launch_bounds__(256) void k_scan2(const int* __restrict__ deg,
                                               const int* __restrict__ blockOff,
                                               int* __restrict__ rowptr) {
    const int t = threadIdx.x;
    const int gi = blockIdx.x * 256 + t;
    const int4 d4 = ((const int4*)deg)[gi];
    const int lsum = d4.x + d4.y + d4.z + d4.w;
    __shared__ int sh[256];
    sh[t] = lsum;
    __syncthreads();
    for (int o = 1; o < 256; o <<= 1) {
        int add = (t >= o) ? sh[t - o] : 0;
        __syncthreads();
        sh[t] += add;
        __syncthreads();
    }
    int base = blockOff[blockIdx.x] + sh[t] - lsum;
    int i0 = gi * 4;
    rowptr[i0 + 0] = base;
    rowptr[i0 + 1] = base + d4.x;
    rowptr[i0 + 2] = base + d4.x + d4.y;
    rowptr[i0 + 3] = base + d4.x + d4.y + d4.z;
}

// ---------------------------------------------------------------- bucket edges
__global__ __launch_bounds__(256) void k_bucket(const int* __restrict__ src,
                                                const int* __restrict__ dst,
                                                const float* __restrict__ dinv,
                                                const int* __restrict__ rowptr,
                                                int* __restrict__ cursor,
                                                int2* __restrict__ edat) {
    int e = blockIdx.x * 256 + threadIdx.x;
    if (e < N_EDGES) {
        int s = src[e], d = dst[e];
        float w = dinv[s] * dinv[d];
        int pos = rowptr[d] + atomicAdd(&cursor[d], 1);
        edat[pos] = make_int2(s, __float_as_int(w));
    }
}

// ---------------------------------------------------------------- GEMM
// Y[n][c] = bias[c] + sum_k X[n][k] * W[k][c]; fp32 math, fp16 output.
template<int K, int C, bool BN>
__global__ __launch_bounds__(256) void k_gemm(const float* __restrict__ X,
                                              const float* __restrict__ W,
                                              const float* __restrict__ bias,
                                              const float* __restrict__ se,
                                              const float* __restrict__ be,
                                              __half* __restrict__ Y,
                                              int nodesPerBlock) {
    constexpr int CG = C / 4;
    constexpr int NPASS = 256 / CG;
    constexpr int XP = K + 1;
    __shared__ __align__(16) float Ws[K * C];
    __shared__ float Xs[NPASS * XP];
    const int tid = threadIdx.x;
    for (int i = tid; i < K * C; i += 256) Ws[i] = W[i];
    const int cg = tid % CG;
    const int ln = tid / CG;
    const int c0 = cg * 4;
    const float4 bv = *(const float4*)&bias[c0];
    const int blockStart = blockIdx.x * nodesPerBlock;
    const int passes = nodesPerBlock / NPASS;
    for (int p = 0; p < passes; ++p) {
        const int node0 = blockStart + p * NPASS;
        __syncthreads();
        for (int i = tid; i < NPASS * K; i += 256) {
            int lnn = i / K, k = i % K;
            int n = node0 + lnn;
            float v = 0.0f;
            if (n < N_NODES) {
                v = X[(size_t)n * K + k];
                if (BN) v = fmaxf(v * se[k] + be[k], 0.0f);
            }
            Xs[lnn * XP + k] = v;
        }
        __syncthreads();
        const int n = node0 + ln;
        float4 acc = bv;
        const float* xrow = &Xs[ln * XP];
        #pragma unroll 8
        for (int k = 0; k < K; ++k) {
            float f = xrow[k];
            float4 w = *(const float4*)&Ws[k * C + c0];
            acc.x += f * w.x;
            acc.y += f * w.y;
            acc.z += f * w.z;
            acc.w += f * w.w;
        }
        if (n < N_NODES) {
            ushort4 sv;
            sv.x = __half_as_ushort(__float2half_rn(acc.x));
            sv.y = __half_as_ushort(__float2half_rn(acc.y));
            sv.z = __half_as_ushort(__float2half_rn(acc.z));
            sv.w = __half_as_ushort(__float2half_rn(acc.w));
            *(ushort4*)&Y[(size_t)n * C + c0] = sv;
        }
    }
}

// ---------------------------------------------------------------- gather-agg
// Main body: clamp-free 8-wide unroll (contiguous wave-uniform edat loads,
// one shift-add address per h gather) so all 8 misses stay in flight.
// Single clamped tail batch handles the remainder.
template<int C>
__global__ __launch_bounds__(256) void k_gather(const __half* __restrict__ h,
                                                const int* __restrict__ rowptr,
                                                const int2* __restrict__ edat,
                                                const float* __restrict__ gammaP,
                                                int r, int npb,
                                                float* __restrict__ X,
                                                float* __restrict__ bnsum,
                                                float* __restrict__ bnsq) {
    constexpr int WPB = 256 / C;   // node slots per block
    const int c = threadIdx.x % C;
    const int slot = threadIdx.x / C;
    const float g = gammaP[r];
    const float gi = 1.0f - g;
    const int n0 = blockIdx.x * npb;
    const __half* hc = h + c;      // per-lane channel base, hoisted
    float s = 0.0f, sq = 0.0f;
    for (int i = slot; i < npb; i += WPB) {
        int n = n0 + i;
        if (n >= N_NODES) break;
        int rs = rowptr[n], re = rowptr[n + 1];
        float acc = 0.0f;
        int e = rs;
        const int efull = rs + ((re - rs) & ~7);
        for (; e < efull; e += 8) {           // clamp-free main body
            int2 ed[8];
            #pragma unroll
            for (int j = 0; j < 8; ++j) ed[j] = edat[e + j];
            float v[8];
            #pragma unroll
            for (int j = 0; j < 8; ++j)
                v[j] = __half2float(hc[(unsigned)ed[j].x * C]);
            #pragma unroll
            for (int j = 0; j < 8; ++j)
                acc += v[j] * __int_as_float(ed[j].y);
        }
        if (e < re) {                         // single clamped tail batch
            int2 ed[8];
            #pragma unroll
            for (int j = 0; j < 8; ++j) {
                int t = e + j;
                ed[j] = edat[(t < re) ? t : rs];
            }
            float v[8];
            #pragma unroll
            for (int j = 0; j < 8; ++j)
                v[j] = __half2float(hc[(unsigned)ed[j].x * C]);
            #pragma unroll
            for (int j = 0; j < 8; ++j) {
                float w = (e + j < re) ? __int_as_float(ed[j].y) : 0.0f;
                acc += v[j] * w;
            }
        }
        float x = g * acc + gi * __half2float(hc[(unsigned)n * C]);
        X[(size_t)n * C + c] = x;
        s += x;
        sq += x * x;
    }
    __shared__ float red[256];
    red[threadIdx.x] = s;
    __syncthreads();
    if (slot == 0) {
        float t = 0.0f;
        #pragma unroll
        for (int i = 0; i < WPB; ++i) t += red[c + i * C];
        atomicAdd(&bnsum[c], t);
    }
    __syncthreads();
    red[threadIdx.x] = sq;
    __syncthreads();
    if (slot == 0) {
        float t = 0.0f;
        #pragma unroll
        for (int i = 0; i < WPB; ++i) t += red[c + i * C];
        atomicAdd(&bnsq[c], t);
    }
}

// ---------------------------------------------------------------- BN finalize
template<int C>
__global__ void k_bnfin(const float* __restrict__ bnsum,
                        const float* __restrict__ bnsq,
                        const float* __restrict__ scale,
                        const float* __restrict__ bias,
                        float* __restrict__ se, float* __restrict__ be) {
    int c = threadIdx.x;
    if (c < C) {
        float m = bnsum[c] * (1.0f / N_NODES);
        float v = bnsq[c] * (1.0f / N_NODES) - m * m;
        float inv = rsqrtf(v + BN_EPS);
        float sc = inv * scale[c];
        se[c] = sc;
        be[c] = bias[c] - m * sc;
    }
}

// ---------------------------------------------------------------- output
__global__ __launch_bounds__(256) void k_out(const float* __restrict__ x2,
                                             const int* __restrict__ batch,
                                             const float* __restrict__ se,
                                             const float* __restrict__ be,
                                             float* __restrict__ out, int r) {
    int gid = blockIdx.x * 256 + threadIdx.x;
    int b = gid >> 5;
    int c = gid & 31;
    if (b < B_NODES) {
        int node = batch[b];
        float y = fmaxf(x2[(size_t)node * 32 + c] * se[c] + be[c], 0.0f);
        float m = y;
        #pragma unroll
        for (int off = 16; off; off >>= 1) m = fmaxf(m, __shfl_xor(m, off, 32));
        float ex = __expf(y - m);
        float ssum = ex;
        #pragma unroll
        for (int off = 16; off; off >>= 1) ssum += __shfl_xor(ssum, off, 32);
        out[(size_t)b * (N_REL * 32) + r * 32 + c] = (y - m) - __logf(ssum);
    }
}

// ---------------------------------------------------------------- launcher
extern "C" void kernel_launch(void* const* d_in, const int* in_sizes, int n_in,
                              void* d_out, int out_size, void* d_ws, size_t ws_size,
                              hipStream_t stream) {
    const float* features    = (const float*)d_in[0];
    const int*   edge_index  = (const int*)d_in[1];
    const int*   batch_nodes = (const int*)d_in[2];
    const float* W1          = (const float*)d_in[3];
    const float* b1          = (const float*)d_in[4];
    const float* W2          = (const float*)d_in[5];
    const float* b2          = (const float*)d_in[6];
    const float* gamma1      = (const float*)d_in[7];
    const float* gamma2      = (const float*)d_in[8];
    const float* bn1_scale   = (const float*)d_in[9];
    const float* bn1_bias    = (const float*)d_in[10];
    const float* bn2_scale   = (const float*)d_in[11];
    const float* bn2_bias    = (const float*)d_in[12];
    float* out = (float*)d_out;

    // ---- workspace layout (byte offsets, 16B aligned) ----
    char* wsB = (char*)d_ws;
    size_t off = 0;
    auto alloc = [&](size_t bytes) {
        void* p = wsB + off;
        off = (off + bytes + 15) & ~(size_t)15;
        return p;
    };
    // zero-region (one memset/relation): deg (padded) + cursor + bn sums
    int*   deg    = (int*)alloc((size_t)N_PAD * 4);
    int*   cursor = (int*)alloc((size_t)N_NODES * 4);
    float* bnsum1 = (float*)alloc(64 * 4);
    float* bnsq1  = (float*)alloc(64 * 4);
    float* bnsum2 = (float*)alloc(32 * 4);
    float* bnsq2  = (float*)alloc(32 * 4);
    const size_t zeroBytes = off;
    // non-zeroed scratch
    float* dinv      = (float*)alloc((size_t)N_NODES * 4);
    int*   rowptr    = (int*)alloc((size_t)(N_PAD + 1) * 4);
    int*   blockSums = (int*)alloc(128 * 4);
    int*   blockOff  = (int*)alloc(128 * 4);
    float* se1 = (float*)alloc(64 * 4);
    float* be1 = (float*)alloc(64 * 4);
    float* se2 = (float*)alloc(32 * 4);
    float* be2 = (float*)alloc(32 * 4);
    int2*   edat = (int2*)alloc((size_t)N_EDGES * 8);
    __half* h1   = (__half*)alloc((size_t)N_NODES * 64 * 2);   // fp16
    float*  x1   = (float*)alloc((size_t)N_NODES * 64 * 4);
    __half* h2   = (__half*)alloc((size_t)N_NODES * 32 * 2);   // fp16
    float*  x2   = (float*)h1;  // alias: h1 (12.8MB) dead after gather<64>

    const int nScanBlocks = N_PAD / 1024;  // 98

    for (int r = 0; r < N_REL; ++r) {
        const int* src = edge_index + (size_t)r * 2 * N_EDGES;
        const int* dst = src + N_EDGES;

        hipMemsetAsync(d_ws, 0, zeroBytes, stream);

        // ---- CSR build (reused by both convs) ----
        k_deg<<<(N_EDGES + 255) / 256, 256, 0, stream>>>(dst, deg);
        k_dinv<<<(N_NODES + 255) / 256, 256, 0, stream>>>(deg, dinv);
        k_blocksum<<<nScanBlocks, 256, 0, stream>>>(deg, blockSums);
        k_scanoff<<<1, 128, 0, stream>>>(blockSums, blockOff, rowptr, nScanBlocks);
        k_scan2<<<nScanBlocks, 256, 0, stream>>>(deg, blockOff, rowptr);
        k_bucket<<<(N_EDGES + 255) / 256, 256, 0, stream>>>(src, dst, dinv,
                                                            rowptr, cursor, edat);

        // ---- conv1 ----
        k_gemm<128, 64, false><<<(N_NODES + 63) / 64, 256, 0, stream>>>(
            features, W1 + (size_t)r * 128 * 64, b1 + r * 64,
            nullptr, nullptr, h1, 64);
        k_gather<64><<<(N_NODES + 31) / 32, 256, 0, stream>>>(
            h1, rowptr, edat, gamma1, r, 32, x1, bnsum1, bnsq1);
        k_bnfin<64><<<1, 64, 0, stream>>>(bnsum1, bnsq1,
            bn1_scale + r * 64, bn1_bias + r * 64, se1, be1);

        // ---- conv2 (BN+relu fused into GEMM load) ----
        k_gemm<64, 32, true><<<(N_NODES + 127) / 128, 256, 0, stream>>>(
            x1, W2 + (size_t)r * 64 * 32, b2 + r * 32, se1, be1, h2, 128);
        k_gather<32><<<(N_NODES + 63) / 64, 256, 0, stream>>>(
            h2, rowptr, edat, gamma2, r, 64, x2, bnsum2, bnsq2);
        k_bnfin<32><<<1, 32, 0, stream>>>(bnsum2, bnsq2,
            bn2_scale + r * 32, bn2_bias + r * 32, se2, be2);

        // ---- output ----
        k_out<<<(B_NODES * 32 + 255) / 256, 256, 0, stream>>>(
            x2, batch_nodes, se2, be2, out, r);
    }
}